// Round 1
// baseline (1917.468 us; speedup 1.0000x reference)
//
#include <hip/hip_runtime.h>
#include <math.h>

#define HID 128
constexpr int cN  = 50000;   // nodes
constexpr int cE  = 600000;  // edges
constexpr int cG  = 512;     // graphs
constexpr int cZV = 1800;    // z vocab
constexpr int cP  = 600000;  // positions

__device__ __forceinline__ float eluf(float v) {
    return v > 0.f ? v : (__expf(v) - 1.f);
}

// ---- edge segment starts: eps[e] = lower_bound(pos_batch, e), eps[E] = P ----
__global__ void eps_kernel(const int* __restrict__ pos_batch, int* __restrict__ eps) {
    int e = blockIdx.x * blockDim.x + threadIdx.x;
    if (e > cE) return;
    int lo = 0, hi = cP;
    while (lo < hi) {
        int mid = (lo + hi) >> 1;
        if (pos_batch[mid] < e) lo = mid + 1; else hi = mid;
    }
    eps[e] = lo;
}

// ---- zWe[l][v][c] = sum_k z[v][k] * We[l][k][c]  (3 layers) ----
__global__ void zwe_layers(const float* __restrict__ z, const float* __restrict__ We,
                           float* __restrict__ zWe) {
    __shared__ float zr[HID];
    int v = blockIdx.x, l = blockIdx.y, c = threadIdx.x;
    zr[c] = z[v * HID + c];
    __syncthreads();
    const float* Wl = We + (size_t)l * HID * HID;
    float acc = 0.f;
    #pragma unroll 8
    for (int k = 0; k < HID; ++k) acc += zr[k] * Wl[k * HID + c];
    zWe[((size_t)l * cZV + v) * HID + c] = acc;
}

// ---- zWe1[v] = sum_k z[v][k] * We1[k]  (conv1, H->1) ----
__global__ void zwe1_kernel(const float* __restrict__ z, const float* __restrict__ We1,
                            float* __restrict__ zWe1) {
    int v = blockIdx.x * blockDim.x + threadIdx.x;
    if (v >= cZV) return;
    float acc = 0.f;
    #pragma unroll 8
    for (int k = 0; k < HID; ++k) acc += z[v * HID + k] * We1[k];
    zWe1[v] = acc;
}

// ---- conv1 edge phase: scalar channel. msg = relu(1 + ea1), scatter to dst ----
__global__ void conv1_edge(const int* __restrict__ dst, const int* __restrict__ eps,
                           const int* __restrict__ pos_index, const float* __restrict__ pos_enc,
                           const float* __restrict__ zWe1, const float* __restrict__ be1,
                           float* __restrict__ agg1) {
    int e = blockIdx.x * blockDim.x + threadIdx.x;
    if (e >= cE) return;
    int s = eps[e], t = eps[e + 1];
    float acc = 0.f;
    for (int p = s; p < t; ++p)
        acc += pos_enc[p] * zWe1[pos_index[p]];
    float m = fmaxf(1.f + acc + be1[0], 0.f);
    atomicAdd(&agg1[dst[e]], m);
}

// ---- conv1 node stage A: h[n][c] = elu((1 + agg1[n]) * W0[c] + b0[c]) ----
__global__ void conv1_node_h(const float* __restrict__ agg1, const float* __restrict__ W0,
                             const float* __restrict__ b0, float* __restrict__ h) {
    int i = blockIdx.x * blockDim.x + threadIdx.x;
    if (i >= cN * HID) return;
    int n = i >> 7, c = i & (HID - 1);
    float h0 = 1.f + agg1[n];
    h[i] = eluf(h0 * W0[c] + b0[c]);
}

// ---- convs edge phase: one wave per edge, float2 per lane (128 ch) ----
__global__ __launch_bounds__(256) void convs_edge(
    const int* __restrict__ src, const int* __restrict__ dst,
    const int* __restrict__ eps,
    const int* __restrict__ pos_index, const float* __restrict__ pos_enc,
    const float* __restrict__ zWe,   // [cZV][HID] for this layer
    const float* __restrict__ be,    // [HID]
    const float* __restrict__ x,     // [cN][HID]
    float* __restrict__ agg)         // [cN][HID]
{
    int gid = blockIdx.x * blockDim.x + threadIdx.x;
    int e = gid >> 6;
    int lane = threadIdx.x & 63;
    if (e >= cE) return;
    int s = eps[e], t = eps[e + 1];
    float2 acc = make_float2(0.f, 0.f);
    for (int p = s; p < t; ++p) {
        int v = pos_index[p];
        float w = pos_enc[p];
        float2 zr = ((const float2*)(zWe + (size_t)v * HID))[lane];
        acc.x += w * zr.x;
        acc.y += w * zr.y;
    }
    float2 b2 = ((const float2*)be)[lane];
    int sn = src[e], dn = dst[e];
    float2 xv = ((const float2*)(x + (size_t)sn * HID))[lane];
    float mx = fmaxf(xv.x + acc.x + b2.x, 0.f);
    float my = fmaxf(xv.y + acc.y + b2.y, 0.f);
    atomicAdd(&agg[(size_t)dn * HID + 2 * lane], mx);
    atomicAdd(&agg[(size_t)dn * HID + 2 * lane + 1], my);
}

// ---- node matmul: Y[M][128] = elu((X (+A)) @ W + b) ----
__global__ __launch_bounds__(256) void node_mm(
    const float* __restrict__ X, const float* __restrict__ A,
    const float* __restrict__ W, const float* __restrict__ b,
    float* __restrict__ Y, int M)
{
    __shared__ float Xs[16][HID];
    int r0 = blockIdx.x * 16;
    int t = threadIdx.x;
    // stage 16 rows (+ optional add) as float4
    for (int i = t; i < 16 * HID / 4; i += 256) {
        int row = i >> 5;        // 32 float4 per row
        int col4 = i & 31;
        int gr = r0 + row;
        float4 v = make_float4(0.f, 0.f, 0.f, 0.f);
        if (gr < M) {
            v = ((const float4*)(X + (size_t)gr * HID))[col4];
            if (A) {
                float4 a = ((const float4*)(A + (size_t)gr * HID))[col4];
                v.x += a.x; v.y += a.y; v.z += a.z; v.w += a.w;
            }
        }
        ((float4*)&Xs[row][0])[col4] = v;
    }
    __syncthreads();
    int c = t & (HID - 1);
    int rg = t >> 7;             // 0 or 1: rows rg*8..rg*8+7
    float acc[8];
    float bc = b[c];
    #pragma unroll
    for (int r = 0; r < 8; ++r) acc[r] = bc;
    #pragma unroll 4
    for (int k = 0; k < HID; ++k) {
        float w = W[k * HID + c];
        #pragma unroll
        for (int r = 0; r < 8; ++r) acc[r] += Xs[rg * 8 + r][k] * w;
    }
    #pragma unroll
    for (int r = 0; r < 8; ++r) {
        int gr = r0 + rg * 8 + r;
        if (gr < M) Y[(size_t)gr * HID + c] = eluf(acc[r]);
    }
}

// ---- pool: atomic segment-sum of x rows into pooled[G][128] ----
__global__ void pool_kernel(const float* __restrict__ x, const int* __restrict__ batch,
                            float* __restrict__ pooled) {
    int i = blockIdx.x * blockDim.x + threadIdx.x;
    if (i >= cN * HID) return;
    int n = i >> 7, c = i & (HID - 1);
    atomicAdd(&pooled[(size_t)batch[n] * HID + c], x[i]);
}

// ---- head: out[g] = elu(pooled[g] @ W1 + b1) @ W2 + b2 ----
__global__ void head_kernel(const float* __restrict__ pooled,
                            const float* __restrict__ W1, const float* __restrict__ b1,
                            const float* __restrict__ W2, const float* __restrict__ b2,
                            float* __restrict__ out) {
    __shared__ float ps[HID];
    __shared__ float hs[HID];
    int g = blockIdx.x, t = threadIdx.x;
    ps[t] = pooled[(size_t)g * HID + t];
    __syncthreads();
    float acc = b1[t];
    #pragma unroll 8
    for (int k = 0; k < HID; ++k) acc += ps[k] * W1[k * HID + t];
    hs[t] = eluf(acc);
    __syncthreads();
    if (t < 10) {
        float o = b2[t];
        #pragma unroll 8
        for (int ch = 0; ch < HID; ++ch) o += hs[ch] * W2[ch * 10 + t];
        out[(size_t)g * 10 + t] = o;
    }
}

extern "C" void kernel_launch(void* const* d_in, const int* in_sizes, int n_in,
                              void* d_out, int out_size, void* d_ws, size_t ws_size,
                              hipStream_t stream) {
    const int*   ei        = (const int*)d_in[0];   // [2][E]
    const int*   batch     = (const int*)d_in[1];   // [N]
    const int*   pos_index = (const int*)d_in[2];   // [P]
    const float* pos_enc   = (const float*)d_in[3]; // [P]
    const int*   pos_batch = (const int*)d_in[4];   // [P]
    const float* z         = (const float*)d_in[5]; // [ZV][H]
    const float* c1W0      = (const float*)d_in[6]; // [1][H]
    const float* c1b0      = (const float*)d_in[7];
    const float* c1W1      = (const float*)d_in[8]; // [H][H]
    const float* c1b1      = (const float*)d_in[9];
    const float* c1We      = (const float*)d_in[10]; // [H][1]
    const float* c1be      = (const float*)d_in[11]; // [1]
    const float* cW0       = (const float*)d_in[12]; // [3][H][H]
    const float* cb0       = (const float*)d_in[13];
    const float* cW1       = (const float*)d_in[14];
    const float* cb1       = (const float*)d_in[15];
    const float* cWe       = (const float*)d_in[16]; // [3][H][H]
    const float* cbe       = (const float*)d_in[17]; // [3][H]
    const float* l1W       = (const float*)d_in[18];
    const float* l1b       = (const float*)d_in[19];
    const float* l2W       = (const float*)d_in[20];
    const float* l2b       = (const float*)d_in[21];
    float* out = (float*)d_out;

    char* ws = (char*)d_ws;
    size_t off = 0;
    auto alloc = [&](size_t bytes) -> void* {
        void* p = ws + off;
        off += (bytes + 511) & ~(size_t)511;
        return p;
    };
    float* zWe3   = (float*)alloc((size_t)3 * cZV * HID * 4);
    float* zWe1   = (float*)alloc((size_t)cZV * 4);
    int*   eps    = (int*)  alloc((size_t)(cE + 1) * 4);
    float* x      = (float*)alloc((size_t)cN * HID * 4);
    float* h      = (float*)alloc((size_t)cN * HID * 4);
    float* agg    = (float*)alloc((size_t)cN * HID * 4);
    float* agg1   = (float*)alloc((size_t)cN * 4);
    float* pooled = (float*)alloc((size_t)cG * HID * 4);

    // precompute: edge segment starts + z@We tables
    eps_kernel<<<(cE + 1 + 255) / 256, 256, 0, stream>>>(pos_batch, eps);
    zwe_layers<<<dim3(cZV, 3), HID, 0, stream>>>(z, cWe, zWe3);
    zwe1_kernel<<<(cZV + 255) / 256, 256, 0, stream>>>(z, c1We, zWe1);

    // conv1
    hipMemsetAsync(agg1, 0, (size_t)cN * 4, stream);
    conv1_edge<<<(cE + 255) / 256, 256, 0, stream>>>(ei + cE, eps, pos_index, pos_enc,
                                                     zWe1, c1be, agg1);
    conv1_node_h<<<(cN * HID + 255) / 256, 256, 0, stream>>>(agg1, c1W0, c1b0, h);
    node_mm<<<(cN + 15) / 16, 256, 0, stream>>>(h, nullptr, c1W1, c1b1, x, cN);

    // convs 0..2
    for (int l = 0; l < 3; ++l) {
        hipMemsetAsync(agg, 0, (size_t)cN * HID * 4, stream);
        convs_edge<<<cE / 4, 256, 0, stream>>>(ei, ei + cE, eps, pos_index, pos_enc,
                                               zWe3 + (size_t)l * cZV * HID,
                                               cbe + (size_t)l * HID, x, agg);
        node_mm<<<(cN + 15) / 16, 256, 0, stream>>>(x, agg, cW0 + (size_t)l * HID * HID,
                                                    cb0 + (size_t)l * HID, h, cN);
        node_mm<<<(cN + 15) / 16, 256, 0, stream>>>(h, nullptr, cW1 + (size_t)l * HID * HID,
                                                    cb1 + (size_t)l * HID, x, cN);
    }

    // pool + head
    hipMemsetAsync(pooled, 0, (size_t)cG * HID * 4, stream);
    pool_kernel<<<(cN * HID + 255) / 256, 256, 0, stream>>>(x, batch, pooled);
    head_kernel<<<cG, HID, 0, stream>>>(pooled, l1W, l1b, l2W, l2b, out);
}

// Round 2
// 1039.484 us; speedup vs baseline: 1.8446x; 1.8446x over previous
//
#include <hip/hip_runtime.h>
#include <math.h>

#define HID 128
constexpr int cN  = 50000;   // nodes
constexpr int cE  = 600000;  // edges
constexpr int cG  = 512;     // graphs
constexpr int cZV = 1800;    // z vocab
constexpr int cP  = 600000;  // positions
constexpr int NB  = (cN + 511) / 512;   // scan blocks = 98

__device__ __forceinline__ float eluf(float v) {
    return v > 0.f ? v : (__expf(v) - 1.f);
}

// ---- edge segment starts: eps[e] = lower_bound(pos_batch, e), eps[E] = P ----
__global__ void eps_kernel(const int* __restrict__ pos_batch, int* __restrict__ eps) {
    int e = blockIdx.x * blockDim.x + threadIdx.x;
    if (e > cE) return;
    int lo = 0, hi = cP;
    while (lo < hi) {
        int mid = (lo + hi) >> 1;
        if (pos_batch[mid] < e) lo = mid + 1; else hi = mid;
    }
    eps[e] = lo;
}

// ---- graph starts: gs[g] = lower_bound(batch, g), gs[G] = N ----
__global__ void gs_kernel(const int* __restrict__ batch, int* __restrict__ gs) {
    int g = blockIdx.x * blockDim.x + threadIdx.x;
    if (g > cG) return;
    int lo = 0, hi = cN;
    while (lo < hi) {
        int mid = (lo + hi) >> 1;
        if (batch[mid] < g) lo = mid + 1; else hi = mid;
    }
    gs[g] = lo;
}

// ---- zWe[l][v][c] = sum_k z[v][k] * We[l][k][c]  (3 layers) ----
__global__ void zwe_layers(const float* __restrict__ z, const float* __restrict__ We,
                           float* __restrict__ zWe) {
    __shared__ float zr[HID];
    int v = blockIdx.x, l = blockIdx.y, c = threadIdx.x;
    zr[c] = z[v * HID + c];
    __syncthreads();
    const float* Wl = We + (size_t)l * HID * HID;
    float acc = 0.f;
    #pragma unroll 8
    for (int k = 0; k < HID; ++k) acc += zr[k] * Wl[k * HID + c];
    zWe[((size_t)l * cZV + v) * HID + c] = acc;
}

// ---- zWe1[v] = sum_k z[v][k] * We1[k]  (conv1, H->1) ----
__global__ void zwe1_kernel(const float* __restrict__ z, const float* __restrict__ We1,
                            float* __restrict__ zWe1) {
    int v = blockIdx.x * blockDim.x + threadIdx.x;
    if (v >= cZV) return;
    float acc = 0.f;
    #pragma unroll 8
    for (int k = 0; k < HID; ++k) acc += z[v * HID + k] * We1[k];
    zWe1[v] = acc;
}

// ======================= CSR build (once per call) =======================
__global__ void deg_kernel(const int* __restrict__ dst, int* __restrict__ deg) {
    int e = blockIdx.x * blockDim.x + threadIdx.x;
    if (e >= cE) return;
    atomicAdd(&deg[dst[e]], 1);
}

__global__ void scan1(const int* __restrict__ deg, int* __restrict__ rowptr,
                      int* __restrict__ bsum) {
    __shared__ int t[512];
    int i = blockIdx.x * 512 + threadIdx.x;
    int v = (i < cN) ? deg[i] : 0;
    t[threadIdx.x] = v;
    __syncthreads();
    for (int off = 1; off < 512; off <<= 1) {
        int add = (threadIdx.x >= off) ? t[threadIdx.x - off] : 0;
        __syncthreads();
        t[threadIdx.x] += add;
        __syncthreads();
    }
    if (i < cN) rowptr[i + 1] = t[threadIdx.x];
    if (threadIdx.x == 511) bsum[blockIdx.x] = t[511];
}

__global__ void scan2(const int* __restrict__ bsum, int* __restrict__ boffs) {
    __shared__ int t[128];
    int i = threadIdx.x;
    int v = (i < NB) ? bsum[i] : 0;
    t[i] = v;
    __syncthreads();
    for (int off = 1; off < 128; off <<= 1) {
        int add = (i >= off) ? t[i - off] : 0;
        __syncthreads();
        t[i] += add;
        __syncthreads();
    }
    if (i < NB) boffs[i] = t[i] - v;   // exclusive prefix
}

__global__ void scan3(int* __restrict__ rowptr, int* __restrict__ cursor,
                      const int* __restrict__ boffs) {
    int i = blockIdx.x * blockDim.x + threadIdx.x;
    if (i == 0) { rowptr[0] = 0; cursor[0] = 0; }
    if (i < cN) {
        int val = rowptr[i + 1] + boffs[i >> 9];
        rowptr[i + 1] = val;
        cursor[i + 1] = val;
    }
}

__global__ void csr_scatter(const int* __restrict__ dst, int* __restrict__ cursor,
                            int* __restrict__ csr_eid) {
    int e = blockIdx.x * blockDim.x + threadIdx.x;
    if (e >= cE) return;
    int p = atomicAdd(&cursor[dst[e]], 1);
    csr_eid[p] = e;
}

// deterministic order within each node's segment
__global__ void csr_sort(const int* __restrict__ rowptr, int* __restrict__ eid) {
    int n = blockIdx.x * blockDim.x + threadIdx.x;
    if (n >= cN) return;
    int a = rowptr[n], b = rowptr[n + 1];
    for (int i = a + 1; i < b; ++i) {
        int v = eid[i];
        int j = i - 1;
        while (j >= a && eid[j] > v) { eid[j + 1] = eid[j]; --j; }
        eid[j + 1] = v;
    }
}

// ======================= conv1 (gather, fused node stage A) =======================
// h[n][c] = elu((1 + sum_e relu(1 + ea1[e] + be1)) * W0[c] + b0[c])
__global__ __launch_bounds__(256) void conv1_gather(
    const int* __restrict__ rowptr, const int* __restrict__ csr_eid,
    const int* __restrict__ eps,
    const int* __restrict__ pos_index, const float* __restrict__ pos_enc,
    const float* __restrict__ zWe1, const float* __restrict__ be1,
    const float* __restrict__ W0, const float* __restrict__ b0,
    float* __restrict__ h)
{
    int n = blockIdx.x * 4 + (threadIdx.x >> 6);
    int lane = threadIdx.x & 63;
    if (n >= cN) return;
    int e0 = rowptr[n], e1 = rowptr[n + 1];
    float be = be1[0];
    float part = 0.f;
    for (int i = e0 + lane; i < e1; i += 64) {
        int e = csr_eid[i];
        int s = eps[e], t = eps[e + 1];
        float a = 0.f;
        for (int p = s; p < t; ++p)
            a += pos_enc[p] * zWe1[pos_index[p]];
        part += fmaxf(1.f + a + be, 0.f);
    }
    #pragma unroll
    for (int off = 32; off > 0; off >>= 1)
        part += __shfl_xor(part, off);
    float h0 = 1.f + part;
    float2 w2 = ((const float2*)W0)[lane];
    float2 b2 = ((const float2*)b0)[lane];
    float2 o;
    o.x = eluf(h0 * w2.x + b2.x);
    o.y = eluf(h0 * w2.y + b2.y);
    ((float2*)(h + (size_t)n * HID))[lane] = o;
}

// ======================= convs edge phase (gather, fused +x) =======================
// h[n][:] = x[n][:] + sum_{e: dst==n} relu(x[src[e]][:] + zWe-sum + be)
__global__ __launch_bounds__(256) void convs_gather(
    const int* __restrict__ rowptr, const int* __restrict__ csr_eid,
    const int* __restrict__ src,
    const int* __restrict__ eps,
    const int* __restrict__ pos_index, const float* __restrict__ pos_enc,
    const float* __restrict__ zWe,   // [cZV][HID] for this layer
    const float* __restrict__ be,    // [HID]
    const float* __restrict__ x,     // [cN][HID]
    float* __restrict__ h)           // [cN][HID]
{
    int n = blockIdx.x * 4 + (threadIdx.x >> 6);
    int lane = threadIdx.x & 63;
    if (n >= cN) return;
    int e0 = rowptr[n], e1 = rowptr[n + 1];
    float2 b2 = ((const float2*)be)[lane];
    float2 acc = make_float2(0.f, 0.f);
    for (int i = e0; i < e1; ++i) {
        int e = csr_eid[i];
        int s = eps[e], t = eps[e + 1];
        float2 z2 = make_float2(0.f, 0.f);
        for (int p = s; p < t; ++p) {
            int v = pos_index[p];
            float w = pos_enc[p];
            float2 zr = ((const float2*)(zWe + (size_t)v * HID))[lane];
            z2.x += w * zr.x;
            z2.y += w * zr.y;
        }
        int sn = src[e];
        float2 xv = ((const float2*)(x + (size_t)sn * HID))[lane];
        acc.x += fmaxf(xv.x + z2.x + b2.x, 0.f);
        acc.y += fmaxf(xv.y + z2.y + b2.y, 0.f);
    }
    float2 xn = ((const float2*)(x + (size_t)n * HID))[lane];
    float2 o;
    o.x = xn.x + acc.x;
    o.y = xn.y + acc.y;
    ((float2*)(h + (size_t)n * HID))[lane] = o;
}

// ---- node matmul: Y[M][128] = elu(X @ W + b). In-place safe (Y == X). ----
__global__ __launch_bounds__(256) void node_mm(
    const float* __restrict__ X,
    const float* __restrict__ W, const float* __restrict__ b,
    float* __restrict__ Y, int M)
{
    __shared__ float Xs[16][HID];
    int r0 = blockIdx.x * 16;
    int t = threadIdx.x;
    for (int i = t; i < 16 * HID / 4; i += 256) {
        int row = i >> 5;
        int col4 = i & 31;
        int gr = r0 + row;
        float4 v = make_float4(0.f, 0.f, 0.f, 0.f);
        if (gr < M) v = ((const float4*)(X + (size_t)gr * HID))[col4];
        ((float4*)&Xs[row][0])[col4] = v;
    }
    __syncthreads();
    int c = t & (HID - 1);
    int rg = t >> 7;
    float acc[8];
    float bc = b[c];
    #pragma unroll
    for (int r = 0; r < 8; ++r) acc[r] = bc;
    #pragma unroll 4
    for (int k = 0; k < HID; ++k) {
        float w = W[k * HID + c];
        #pragma unroll
        for (int r = 0; r < 8; ++r) acc[r] += Xs[rg * 8 + r][k] * w;
    }
    #pragma unroll
    for (int r = 0; r < 8; ++r) {
        int gr = r0 + rg * 8 + r;
        if (gr < M) Y[(size_t)gr * HID + c] = eluf(acc[r]);
    }
}

// ---- fused pool + head: out[g] = elu(sum_n x[n] @ W1 + b1) @ W2 + b2 ----
__global__ void pool_head(const float* __restrict__ x, const int* __restrict__ gs,
                          const float* __restrict__ W1, const float* __restrict__ b1,
                          const float* __restrict__ W2, const float* __restrict__ b2,
                          float* __restrict__ out) {
    __shared__ float ps[HID];
    __shared__ float hs[HID];
    int g = blockIdx.x, t = threadIdx.x;
    int n0 = gs[g], n1 = gs[g + 1];
    float acc = 0.f;
    for (int n = n0; n < n1; ++n) acc += x[(size_t)n * HID + t];
    ps[t] = acc;
    __syncthreads();
    float a = b1[t];
    #pragma unroll 8
    for (int k = 0; k < HID; ++k) a += ps[k] * W1[k * HID + t];
    hs[t] = eluf(a);
    __syncthreads();
    if (t < 10) {
        float o = b2[t];
        #pragma unroll 8
        for (int ch = 0; ch < HID; ++ch) o += hs[ch] * W2[ch * 10 + t];
        out[(size_t)g * 10 + t] = o;
    }
}

extern "C" void kernel_launch(void* const* d_in, const int* in_sizes, int n_in,
                              void* d_out, int out_size, void* d_ws, size_t ws_size,
                              hipStream_t stream) {
    const int*   ei        = (const int*)d_in[0];   // [2][E]
    const int*   batch     = (const int*)d_in[1];   // [N]
    const int*   pos_index = (const int*)d_in[2];   // [P]
    const float* pos_enc   = (const float*)d_in[3]; // [P]
    const int*   pos_batch = (const int*)d_in[4];   // [P]
    const float* z         = (const float*)d_in[5]; // [ZV][H]
    const float* c1W0      = (const float*)d_in[6]; // [1][H]
    const float* c1b0      = (const float*)d_in[7];
    const float* c1W1      = (const float*)d_in[8]; // [H][H]
    const float* c1b1      = (const float*)d_in[9];
    const float* c1We      = (const float*)d_in[10]; // [H][1]
    const float* c1be      = (const float*)d_in[11]; // [1]
    const float* cW0       = (const float*)d_in[12]; // [3][H][H]
    const float* cb0       = (const float*)d_in[13];
    const float* cW1       = (const float*)d_in[14];
    const float* cb1       = (const float*)d_in[15];
    const float* cWe       = (const float*)d_in[16]; // [3][H][H]
    const float* cbe       = (const float*)d_in[17]; // [3][H]
    const float* l1W       = (const float*)d_in[18];
    const float* l1b       = (const float*)d_in[19];
    const float* l2W       = (const float*)d_in[20];
    const float* l2b       = (const float*)d_in[21];
    float* out = (float*)d_out;

    const int* src = ei;
    const int* dst = ei + cE;

    char* ws = (char*)d_ws;
    size_t off = 0;
    auto alloc = [&](size_t bytes) -> void* {
        void* p = ws + off;
        off += (bytes + 511) & ~(size_t)511;
        return p;
    };
    float* zWe3    = (float*)alloc((size_t)3 * cZV * HID * 4);
    float* zWe1    = (float*)alloc((size_t)cZV * 4);
    int*   eps     = (int*)  alloc((size_t)(cE + 1) * 4);
    float* x       = (float*)alloc((size_t)cN * HID * 4);
    float* h       = (float*)alloc((size_t)cN * HID * 4);
    int*   deg     = (int*)  alloc((size_t)cN * 4);
    int*   rowptr  = (int*)  alloc((size_t)(cN + 1) * 4);
    int*   cursor  = (int*)  alloc((size_t)(cN + 1) * 4);
    int*   csr_eid = (int*)  alloc((size_t)cE * 4);
    int*   bsum    = (int*)  alloc((size_t)NB * 4);
    int*   boffs   = (int*)  alloc((size_t)NB * 4);
    int*   gs      = (int*)  alloc((size_t)(cG + 1) * 4);

    // precompute: segment starts + z@We tables
    eps_kernel<<<(cE + 1 + 255) / 256, 256, 0, stream>>>(pos_batch, eps);
    gs_kernel<<<(cG + 1 + 127) / 128, 128, 0, stream>>>(batch, gs);
    zwe_layers<<<dim3(cZV, 3), HID, 0, stream>>>(z, cWe, zWe3);
    zwe1_kernel<<<(cZV + 255) / 256, 256, 0, stream>>>(z, c1We, zWe1);

    // CSR build (dst is fixed across layers)
    hipMemsetAsync(deg, 0, (size_t)cN * 4, stream);
    deg_kernel<<<(cE + 255) / 256, 256, 0, stream>>>(dst, deg);
    scan1<<<NB, 512, 0, stream>>>(deg, rowptr, bsum);
    scan2<<<1, 128, 0, stream>>>(bsum, boffs);
    scan3<<<(cN + 255) / 256, 256, 0, stream>>>(rowptr, cursor, boffs);
    csr_scatter<<<(cE + 255) / 256, 256, 0, stream>>>(dst, cursor, csr_eid);
    csr_sort<<<(cN + 255) / 256, 256, 0, stream>>>(rowptr, csr_eid);

    // conv1
    conv1_gather<<<(cN + 3) / 4, 256, 0, stream>>>(rowptr, csr_eid, eps,
                                                   pos_index, pos_enc,
                                                   zWe1, c1be, c1W0, c1b0, h);
    node_mm<<<(cN + 15) / 16, 256, 0, stream>>>(h, c1W1, c1b1, x, cN);

    // convs 0..2
    for (int l = 0; l < 3; ++l) {
        convs_gather<<<(cN + 3) / 4, 256, 0, stream>>>(rowptr, csr_eid, src, eps,
                                                       pos_index, pos_enc,
                                                       zWe3 + (size_t)l * cZV * HID,
                                                       cbe + (size_t)l * HID, x, h);
        node_mm<<<(cN + 15) / 16, 256, 0, stream>>>(h, cW0 + (size_t)l * HID * HID,
                                                    cb0 + (size_t)l * HID, h, cN);
        node_mm<<<(cN + 15) / 16, 256, 0, stream>>>(h, cW1 + (size_t)l * HID * HID,
                                                    cb1 + (size_t)l * HID, x, cN);
    }

    // pool + head
    pool_head<<<cG, HID, 0, stream>>>(x, gs, l1W, l1b, l2W, l2b, out);
}

// Round 3
// 817.499 us; speedup vs baseline: 2.3455x; 1.2715x over previous
//
#include <hip/hip_runtime.h>
#include <hip/hip_bf16.h>
#include <math.h>

#define HID 128
constexpr int cN  = 50000;   // nodes
constexpr int cE  = 600000;  // edges
constexpr int cG  = 512;     // graphs
constexpr int cZV = 1800;    // z vocab
constexpr int cP  = 600000;  // positions
constexpr int NB  = (cN + 511) / 512;   // scan blocks = 98

typedef unsigned int uint32;
typedef unsigned short ushort16;

__device__ __forceinline__ float eluf(float v) {
    return v > 0.f ? v : (__expf(v) - 1.f);
}

// bf16 pair (packed in uint32, little-endian: low 16 = elem0) -> float2
__device__ __forceinline__ float2 bf2f2(uint32 u) {
    float2 r;
    r.x = __uint_as_float(u << 16);
    r.y = __uint_as_float(u & 0xffff0000u);
    return r;
}

// float -> bf16 (RNE)
__device__ __forceinline__ ushort16 f2bf(float f) {
    uint32 u = __float_as_uint(f);
    u += 0x7fffu + ((u >> 16) & 1u);
    return (ushort16)(u >> 16);
}

// ---- edge segment starts: eps[e] = lower_bound(pos_batch, e), eps[E] = P ----
__global__ void eps_kernel(const int* __restrict__ pos_batch, int* __restrict__ eps) {
    int e = blockIdx.x * blockDim.x + threadIdx.x;
    if (e > cE) return;
    int lo = 0, hi = cP;
    while (lo < hi) {
        int mid = (lo + hi) >> 1;
        if (pos_batch[mid] < e) lo = mid + 1; else hi = mid;
    }
    eps[e] = lo;
}

// ---- graph starts: gs[g] = lower_bound(batch, g), gs[G] = N ----
__global__ void gs_kernel(const int* __restrict__ batch, int* __restrict__ gs) {
    int g = blockIdx.x * blockDim.x + threadIdx.x;
    if (g > cG) return;
    int lo = 0, hi = cN;
    while (lo < hi) {
        int mid = (lo + hi) >> 1;
        if (batch[mid] < g) lo = mid + 1; else hi = mid;
    }
    gs[g] = lo;
}

// ---- zWe (bf16): zWe[l][v][c] = sum_k z[v][k] * We[l][k][c]  (3 layers) ----
__global__ void zwe_layers(const float* __restrict__ z, const float* __restrict__ We,
                           ushort16* __restrict__ zWeb) {
    __shared__ float zr[HID];
    int v = blockIdx.x, l = blockIdx.y, c = threadIdx.x;
    zr[c] = z[v * HID + c];
    __syncthreads();
    const float* Wl = We + (size_t)l * HID * HID;
    float acc = 0.f;
    #pragma unroll 8
    for (int k = 0; k < HID; ++k) acc += zr[k] * Wl[k * HID + c];
    zWeb[((size_t)l * cZV + v) * HID + c] = f2bf(acc);
}

// ---- zWe1[v] = sum_k z[v][k] * We1[k]  (conv1, H->1, fp32) ----
__global__ void zwe1_kernel(const float* __restrict__ z, const float* __restrict__ We1,
                            float* __restrict__ zWe1) {
    int v = blockIdx.x * blockDim.x + threadIdx.x;
    if (v >= cZV) return;
    float acc = 0.f;
    #pragma unroll 8
    for (int k = 0; k < HID; ++k) acc += z[v * HID + k] * We1[k];
    zWe1[v] = acc;
}

// ======================= CSR build (once per call) =======================
__global__ void deg_kernel(const int* __restrict__ dst, int* __restrict__ deg) {
    int e = blockIdx.x * blockDim.x + threadIdx.x;
    if (e >= cE) return;
    atomicAdd(&deg[dst[e]], 1);
}

__global__ void scan1(const int* __restrict__ deg, int* __restrict__ rowptr,
                      int* __restrict__ bsum) {
    __shared__ int t[512];
    int i = blockIdx.x * 512 + threadIdx.x;
    int v = (i < cN) ? deg[i] : 0;
    t[threadIdx.x] = v;
    __syncthreads();
    for (int off = 1; off < 512; off <<= 1) {
        int add = (threadIdx.x >= off) ? t[threadIdx.x - off] : 0;
        __syncthreads();
        t[threadIdx.x] += add;
        __syncthreads();
    }
    if (i < cN) rowptr[i + 1] = t[threadIdx.x];
    if (threadIdx.x == 511) bsum[blockIdx.x] = t[511];
}

__global__ void scan2(const int* __restrict__ bsum, int* __restrict__ boffs) {
    __shared__ int t[128];
    int i = threadIdx.x;
    int v = (i < NB) ? bsum[i] : 0;
    t[i] = v;
    __syncthreads();
    for (int off = 1; off < 128; off <<= 1) {
        int add = (i >= off) ? t[i - off] : 0;
        __syncthreads();
        t[i] += add;
        __syncthreads();
    }
    if (i < NB) boffs[i] = t[i] - v;   // exclusive prefix
}

__global__ void scan3(int* __restrict__ rowptr, int* __restrict__ cursor,
                      const int* __restrict__ boffs) {
    int i = blockIdx.x * blockDim.x + threadIdx.x;
    if (i == 0) { rowptr[0] = 0; cursor[0] = 0; }
    if (i < cN) {
        int val = rowptr[i + 1] + boffs[i >> 9];
        rowptr[i + 1] = val;
        cursor[i + 1] = val;
    }
}

__global__ void csr_scatter(const int* __restrict__ dst, int* __restrict__ cursor,
                            int* __restrict__ csr_eid) {
    int e = blockIdx.x * blockDim.x + threadIdx.x;
    if (e >= cE) return;
    int p = atomicAdd(&cursor[dst[e]], 1);
    csr_eid[p] = e;
}

// deterministic order within each node's segment
__global__ void csr_sort(const int* __restrict__ rowptr, int* __restrict__ eid) {
    int n = blockIdx.x * blockDim.x + threadIdx.x;
    if (n >= cN) return;
    int a = rowptr[n], b = rowptr[n + 1];
    for (int i = a + 1; i < b; ++i) {
        int v = eid[i];
        int j = i - 1;
        while (j >= a && eid[j] > v) { eid[j + 1] = eid[j]; --j; }
        eid[j + 1] = v;
    }
}

// ======================= conv1 (gather, fused node stage A) =======================
// h[n][c] = elu((1 + sum_e relu(1 + ea1[e] + be1)) * W0[c] + b0[c])
__global__ __launch_bounds__(256) void conv1_gather(
    const int* __restrict__ rowptr, const int* __restrict__ csr_eid,
    const int* __restrict__ eps,
    const int* __restrict__ pos_index, const float* __restrict__ pos_enc,
    const float* __restrict__ zWe1, const float* __restrict__ be1,
    const float* __restrict__ W0, const float* __restrict__ b0,
    float* __restrict__ h)
{
    int n = blockIdx.x * 4 + (threadIdx.x >> 6);
    int lane = threadIdx.x & 63;
    if (n >= cN) return;
    int e0 = rowptr[n], e1 = rowptr[n + 1];
    float be = be1[0];
    float part = 0.f;
    for (int i = e0 + lane; i < e1; i += 64) {
        int e = csr_eid[i];
        int s = eps[e], t = eps[e + 1];
        float a = 0.f;
        for (int p = s; p < t; ++p)
            a += pos_enc[p] * zWe1[pos_index[p]];
        part += fmaxf(1.f + a + be, 0.f);
    }
    #pragma unroll
    for (int off = 32; off > 0; off >>= 1)
        part += __shfl_xor(part, off);
    float h0 = 1.f + part;
    float2 w2 = ((const float2*)W0)[lane];
    float2 b2 = ((const float2*)b0)[lane];
    float2 o;
    o.x = eluf(h0 * w2.x + b2.x);
    o.y = eluf(h0 * w2.y + b2.y);
    ((float2*)(h + (size_t)n * HID))[lane] = o;
}

// ======================= convs edge phase (gather, bf16 operands) =======================
// h[n][:] = x[n][:] + sum_{e: dst==n} relu(x_bf16[src[e]][:] + zWe_bf16-sum + be)
__global__ __launch_bounds__(256) void convs_gather(
    const int* __restrict__ rowptr, const int* __restrict__ csr_eid,
    const int* __restrict__ src,
    const int* __restrict__ eps,
    const int* __restrict__ pos_index, const float* __restrict__ pos_enc,
    const ushort16* __restrict__ zWe,  // [cZV][HID] bf16 for this layer
    const float* __restrict__ be,      // [HID]
    const float* __restrict__ x,       // [cN][HID] fp32 (self term)
    const ushort16* __restrict__ xb,   // [cN][HID] bf16 (gather operand)
    float* __restrict__ h)             // [cN][HID]
{
    int n = blockIdx.x * 4 + (threadIdx.x >> 6);
    int lane = threadIdx.x & 63;
    if (n >= cN) return;
    int e0 = rowptr[n], e1 = rowptr[n + 1];
    float2 b2 = ((const float2*)be)[lane];
    float2 acc = make_float2(0.f, 0.f);
    int i = e0;
    // 2-edge unrolled: two independent load chains in flight
    for (; i + 2 <= e1; i += 2) {
        int eA = csr_eid[i], eB = csr_eid[i + 1];
        int sA = eps[eA], tA = eps[eA + 1];
        int sB = eps[eB], tB = eps[eB + 1];
        int nA = src[eA], nB = src[eB];
        uint32 xAu = ((const uint32*)(xb + (size_t)nA * HID))[lane];
        uint32 xBu = ((const uint32*)(xb + (size_t)nB * HID))[lane];
        float2 zA = make_float2(0.f, 0.f);
        for (int p = sA; p < tA; ++p) {
            int v = pos_index[p];
            float w = pos_enc[p];
            float2 zr = bf2f2(((const uint32*)(zWe + (size_t)v * HID))[lane]);
            zA.x += w * zr.x; zA.y += w * zr.y;
        }
        float2 zB = make_float2(0.f, 0.f);
        for (int p = sB; p < tB; ++p) {
            int v = pos_index[p];
            float w = pos_enc[p];
            float2 zr = bf2f2(((const uint32*)(zWe + (size_t)v * HID))[lane]);
            zB.x += w * zr.x; zB.y += w * zr.y;
        }
        float2 xA = bf2f2(xAu), xB = bf2f2(xBu);
        acc.x += fmaxf(xA.x + zA.x + b2.x, 0.f) + fmaxf(xB.x + zB.x + b2.x, 0.f);
        acc.y += fmaxf(xA.y + zA.y + b2.y, 0.f) + fmaxf(xB.y + zB.y + b2.y, 0.f);
    }
    if (i < e1) {
        int e = csr_eid[i];
        int s = eps[e], t = eps[e + 1];
        int sn = src[e];
        uint32 xu = ((const uint32*)(xb + (size_t)sn * HID))[lane];
        float2 z2 = make_float2(0.f, 0.f);
        for (int p = s; p < t; ++p) {
            int v = pos_index[p];
            float w = pos_enc[p];
            float2 zr = bf2f2(((const uint32*)(zWe + (size_t)v * HID))[lane]);
            z2.x += w * zr.x; z2.y += w * zr.y;
        }
        float2 xv = bf2f2(xu);
        acc.x += fmaxf(xv.x + z2.x + b2.x, 0.f);
        acc.y += fmaxf(xv.y + z2.y + b2.y, 0.f);
    }
    float2 xn = ((const float2*)(x + (size_t)n * HID))[lane];
    float2 o;
    o.x = xn.x + acc.x;
    o.y = xn.y + acc.y;
    ((float2*)(h + (size_t)n * HID))[lane] = o;
}

// ---- node matmul: Y[M][128] = elu(X @ W + b). In-place safe (Y == X). ----
// Optionally writes a bf16 shadow copy Yb for the next layer's gathers.
__global__ __launch_bounds__(256) void node_mm(
    const float* __restrict__ X,
    const float* __restrict__ W, const float* __restrict__ b,
    float* __restrict__ Y, ushort16* __restrict__ Yb, int M)
{
    __shared__ float Xs[16][HID];
    int r0 = blockIdx.x * 16;
    int t = threadIdx.x;
    for (int i = t; i < 16 * HID / 4; i += 256) {
        int row = i >> 5;
        int col4 = i & 31;
        int gr = r0 + row;
        float4 v = make_float4(0.f, 0.f, 0.f, 0.f);
        if (gr < M) v = ((const float4*)(X + (size_t)gr * HID))[col4];
        ((float4*)&Xs[row][0])[col4] = v;
    }
    __syncthreads();
    int c = t & (HID - 1);
    int rg = t >> 7;
    float acc[8];
    float bc = b[c];
    #pragma unroll
    for (int r = 0; r < 8; ++r) acc[r] = bc;
    #pragma unroll 4
    for (int k = 0; k < HID; ++k) {
        float w = W[k * HID + c];
        #pragma unroll
        for (int r = 0; r < 8; ++r) acc[r] += Xs[rg * 8 + r][k] * w;
    }
    #pragma unroll
    for (int r = 0; r < 8; ++r) {
        int gr = r0 + rg * 8 + r;
        if (gr < M) {
            float v = eluf(acc[r]);
            Y[(size_t)gr * HID + c] = v;
            if (Yb) Yb[(size_t)gr * HID + c] = f2bf(v);
        }
    }
}

// ---- fused pool + head: out[g] = elu(sum_n x[n] @ W1 + b1) @ W2 + b2 ----
__global__ void pool_head(const float* __restrict__ x, const int* __restrict__ gs,
                          const float* __restrict__ W1, const float* __restrict__ b1,
                          const float* __restrict__ W2, const float* __restrict__ b2,
                          float* __restrict__ out) {
    __shared__ float ps[HID];
    __shared__ float hs[HID];
    int g = blockIdx.x, t = threadIdx.x;
    int n0 = gs[g], n1 = gs[g + 1];
    float acc = 0.f;
    for (int n = n0; n < n1; ++n) acc += x[(size_t)n * HID + t];
    ps[t] = acc;
    __syncthreads();
    float a = b1[t];
    #pragma unroll 8
    for (int k = 0; k < HID; ++k) a += ps[k] * W1[k * HID + t];
    hs[t] = eluf(a);
    __syncthreads();
    if (t < 10) {
        float o = b2[t];
        #pragma unroll 8
        for (int ch = 0; ch < HID; ++ch) o += hs[ch] * W2[ch * 10 + t];
        out[(size_t)g * 10 + t] = o;
    }
}

extern "C" void kernel_launch(void* const* d_in, const int* in_sizes, int n_in,
                              void* d_out, int out_size, void* d_ws, size_t ws_size,
                              hipStream_t stream) {
    const int*   ei        = (const int*)d_in[0];   // [2][E]
    const int*   batch     = (const int*)d_in[1];   // [N]
    const int*   pos_index = (const int*)d_in[2];   // [P]
    const float* pos_enc   = (const float*)d_in[3]; // [P]
    const int*   pos_batch = (const int*)d_in[4];   // [P]
    const float* z         = (const float*)d_in[5]; // [ZV][H]
    const float* c1W0      = (const float*)d_in[6]; // [1][H]
    const float* c1b0      = (const float*)d_in[7];
    const float* c1W1      = (const float*)d_in[8]; // [H][H]
    const float* c1b1      = (const float*)d_in[9];
    const float* c1We      = (const float*)d_in[10]; // [H][1]
    const float* c1be      = (const float*)d_in[11]; // [1]
    const float* cW0       = (const float*)d_in[12]; // [3][H][H]
    const float* cb0       = (const float*)d_in[13];
    const float* cW1       = (const float*)d_in[14];
    const float* cb1       = (const float*)d_in[15];
    const float* cWe       = (const float*)d_in[16]; // [3][H][H]
    const float* cbe       = (const float*)d_in[17]; // [3][H]
    const float* l1W       = (const float*)d_in[18];
    const float* l1b       = (const float*)d_in[19];
    const float* l2W       = (const float*)d_in[20];
    const float* l2b       = (const float*)d_in[21];
    float* out = (float*)d_out;

    const int* src = ei;
    const int* dst = ei + cE;

    char* ws = (char*)d_ws;
    size_t off = 0;
    auto alloc = [&](size_t bytes) -> void* {
        void* p = ws + off;
        off += (bytes + 511) & ~(size_t)511;
        return p;
    };
    ushort16* zWe3  = (ushort16*)alloc((size_t)3 * cZV * HID * 2);
    float* zWe1     = (float*)alloc((size_t)cZV * 4);
    int*   eps      = (int*)  alloc((size_t)(cE + 1) * 4);
    float* x        = (float*)alloc((size_t)cN * HID * 4);
    float* h        = (float*)alloc((size_t)cN * HID * 4);
    ushort16* xbf   = (ushort16*)alloc((size_t)cN * HID * 2);
    int*   deg      = (int*)  alloc((size_t)cN * 4);
    int*   rowptr   = (int*)  alloc((size_t)(cN + 1) * 4);
    int*   cursor   = (int*)  alloc((size_t)(cN + 1) * 4);
    int*   csr_eid  = (int*)  alloc((size_t)cE * 4);
    int*   bsum     = (int*)  alloc((size_t)NB * 4);
    int*   boffs    = (int*)  alloc((size_t)NB * 4);
    int*   gs       = (int*)  alloc((size_t)(cG + 1) * 4);

    // precompute: segment starts + z@We tables
    eps_kernel<<<(cE + 1 + 255) / 256, 256, 0, stream>>>(pos_batch, eps);
    gs_kernel<<<(cG + 1 + 127) / 128, 128, 0, stream>>>(batch, gs);
    zwe_layers<<<dim3(cZV, 3), HID, 0, stream>>>(z, cWe, zWe3);
    zwe1_kernel<<<(cZV + 255) / 256, 256, 0, stream>>>(z, c1We, zWe1);

    // CSR build (dst is fixed across layers)
    hipMemsetAsync(deg, 0, (size_t)cN * 4, stream);
    deg_kernel<<<(cE + 255) / 256, 256, 0, stream>>>(dst, deg);
    scan1<<<NB, 512, 0, stream>>>(deg, rowptr, bsum);
    scan2<<<1, 128, 0, stream>>>(bsum, boffs);
    scan3<<<(cN + 255) / 256, 256, 0, stream>>>(rowptr, cursor, boffs);
    csr_scatter<<<(cE + 255) / 256, 256, 0, stream>>>(dst, cursor, csr_eid);
    csr_sort<<<(cN + 255) / 256, 256, 0, stream>>>(rowptr, csr_eid);

    // conv1
    conv1_gather<<<(cN + 3) / 4, 256, 0, stream>>>(rowptr, csr_eid, eps,
                                                   pos_index, pos_enc,
                                                   zWe1, c1be, c1W0, c1b0, h);
    node_mm<<<(cN + 15) / 16, 256, 0, stream>>>(h, c1W1, c1b1, x, xbf, cN);

    // convs 0..2
    for (int l = 0; l < 3; ++l) {
        convs_gather<<<(cN + 3) / 4, 256, 0, stream>>>(rowptr, csr_eid, src, eps,
                                                       pos_index, pos_enc,
                                                       zWe3 + (size_t)l * cZV * HID,
                                                       cbe + (size_t)l * HID, x, xbf, h);
        node_mm<<<(cN + 15) / 16, 256, 0, stream>>>(h, cW0 + (size_t)l * HID * HID,
                                                    cb0 + (size_t)l * HID, h, nullptr, cN);
        node_mm<<<(cN + 15) / 16, 256, 0, stream>>>(h, cW1 + (size_t)l * HID * HID,
                                                    cb1 + (size_t)l * HID, x,
                                                    (l < 2) ? xbf : nullptr, cN);
    }

    // pool + head
    pool_head<<<cG, HID, 0, stream>>>(x, gs, l1W, l1b, l2W, l2b, out);
}